// Round 1
// baseline (239.972 us; speedup 1.0000x reference)
//
#include <hip/hip_runtime.h>

#define MAXN 2048

// Builds the deduplicated selection maps, exactly mirroring _fix_duplicates:
//   sel[j]   = rint(clip(w[j], 0, n-1))                 (round-half-even, like jnp.round)
//   dup[j]   = sel[j] seen at an earlier index
//   empties  = values never selected, consumed in DESCENDING order by dup rank
// block 0 -> column map (n=C), block 1 -> row map (n=R)
__global__ void build_map_kernel(const float* __restrict__ wc, const float* __restrict__ wr,
                                 int C, int R,
                                 int* __restrict__ colmap, int* __restrict__ rowmap) {
    const float* w;
    int n;
    int* outmap;
    if (blockIdx.x == 0) { w = wc; n = C; outmap = colmap; }
    else                 { w = wr; n = R; outmap = rowmap; }

    __shared__ int sel[MAXN];
    __shared__ int first[MAXN];
    __shared__ int emptyslot[MAXN];
    __shared__ int dts[256], ets[256];

    const int t = threadIdx.x;
    const int base = t * 8;           // contiguous 8-element segment per thread
    const float upper = (float)(n - 1);

    for (int k = 0; k < 8; k++) {
        int idx = base + k;
        if (idx < n) {
            float v = w[idx];
            v = fminf(fmaxf(v, 0.0f), upper);
            sel[idx]   = (int)rintf(v);      // RNE == jnp.round
            first[idx] = 0x7fffffff;
        }
    }
    __syncthreads();
    for (int k = 0; k < 8; k++) {
        int idx = base + k;
        if (idx < n) atomicMin(&first[sel[idx]], idx);
    }
    __syncthreads();

    int dflag[8], eflag[8];
    int dsum = 0, esum = 0;
    for (int k = 0; k < 8; k++) {
        int idx = base + k;
        if (idx < n) {
            dflag[k] = (first[sel[idx]] != idx) ? 1 : 0;   // non-first occurrence
            eflag[k] = (first[idx] == 0x7fffffff) ? 1 : 0; // value idx never used
        } else { dflag[k] = 0; eflag[k] = 0; }
        dsum += dflag[k]; esum += eflag[k];
    }

    // block-wide inclusive scans (Hillis-Steele over 256 per-thread sums)
    dts[t] = dsum; ets[t] = esum;
    __syncthreads();
    for (int off = 1; off < 256; off <<= 1) {
        int dv = 0, ev = 0;
        if (t >= off) { dv = dts[t - off]; ev = ets[t - off]; }
        __syncthreads();
        dts[t] += dv; ets[t] += ev;
        __syncthreads();
    }
    const int dexc = dts[t] - dsum;   // dups before my segment
    const int eexc = ets[t] - esum;   // empties (by value) below my segment
    const int E    = ets[255];        // total empties (== total dups)

    // scatter empties: value v with (# empties < v) = p goes to slot E-1-p (descending order)
    int erun = eexc;
    for (int k = 0; k < 8; k++) {
        int idx = base + k;
        if (idx < n && eflag[k]) emptyslot[E - 1 - erun] = idx;
        erun += eflag[k];
    }
    __syncthreads();

    // final map: k-th duplicate (index order) takes emptyslot[k]
    int drun = dexc;
    for (int k = 0; k < 8; k++) {
        int idx = base + k;
        if (idx < n) outmap[idx] = dflag[k] ? emptyslot[drun] : sel[idx];
        drun += dflag[k];
    }
}

// out[b, i, j] = x[b, rowmap[i], colmap[j]]
// one block per output row: coalesced float4 row load -> LDS -> gather -> coalesced float4 store
__global__ void gather_kernel(const float* __restrict__ x,
                              const int* __restrict__ rowmap,
                              const int* __restrict__ colmap,
                              float* __restrict__ out,
                              int R, int C) {
    __shared__ float lds[MAXN];
    const int blk = blockIdx.x;
    const int b = blk / R;
    const int i = blk - b * R;
    const int sr = rowmap[i];

    const float4* src4 = (const float4*)(x + ((size_t)b * R + sr) * (size_t)C);
    float4*       dst4 = (float4*)(out + ((size_t)b * R + i) * (size_t)C);
    const int4*  cmap4 = (const int4*)colmap;

    const int t = threadIdx.x;
    const int n4 = C >> 2;  // 512 float4s per row

    for (int k = t; k < n4; k += 256) {
        ((float4*)lds)[k] = src4[k];
    }
    __syncthreads();
    for (int k = t; k < n4; k += 256) {
        int4 c = cmap4[k];
        float4 v;
        v.x = lds[c.x]; v.y = lds[c.y]; v.z = lds[c.z]; v.w = lds[c.w];
        dst4[k] = v;
    }
}

extern "C" void kernel_launch(void* const* d_in, const int* in_sizes, int n_in,
                              void* d_out, int out_size, void* d_ws, size_t ws_size,
                              hipStream_t stream) {
    const float* x  = (const float*)d_in[0];
    const float* wc = (const float*)d_in[1];
    const float* wr = (const float*)d_in[2];
    const int C = in_sizes[1];            // 2048
    const int R = in_sizes[2];            // 1024
    const int B = in_sizes[0] / (R * C);  // 16

    int* colmap = (int*)d_ws;
    int* rowmap = colmap + C;

    build_map_kernel<<<2, 256, 0, stream>>>(wc, wr, C, R, colmap, rowmap);
    gather_kernel<<<B * R, 256, 0, stream>>>(x, rowmap, colmap, (float*)d_out, R, C);
}